// Round 2
// baseline (355.937 us; speedup 1.0000x reference)
//
#include <hip/hip_runtime.h>

// QuantumClassicalInterface on MI355X (gfx950). Round 10.
// f32 I/O. Projections: bf16 MFMA (128^2, BK=64, XOR swizzle) -> fp8 cp8/qp8.
// Gate/Sim/PV: NEW fp8 e4m3 MFMA, BM=256, 8 waves, double-buffered LDS,
// phase-split K-step with raw s_barrier (no __syncthreads vmcnt-drain) and a
// single per-wave vmcnt(0) per K-step issued one full K-step after the loads
// (T3+T4 counted-wait pipeline) + s_setprio around MFMA clusters (T5).
// Softmax fused (exp + atomic row sums; logits bounded so no max-sub needed).
// PV epilogue does final merge: out = classical + g * (P@quantum)/l.
// All big-GEMM launches are exactly 256 blocks = 1 block/CU.

typedef unsigned short u16;
typedef unsigned char u8;
typedef __bf16 bf16x8 __attribute__((ext_vector_type(8)));
typedef float f32x4 __attribute__((ext_vector_type(4)));

__device__ __forceinline__ u16 f2bf(float f) {
    unsigned int x;
    __builtin_memcpy(&x, &f, 4);
    unsigned int r = x + 0x7FFFu + ((x >> 16) & 1u);
    return (u16)(r >> 16);
}
__device__ __forceinline__ float bf2f(u16 u) {
    unsigned int x = ((unsigned int)u) << 16;
    float f;
    __builtin_memcpy(&f, &x, 4);
    return f;
}
__device__ __forceinline__ u8 f2fp8(float f) {
    int p = __builtin_amdgcn_cvt_pk_fp8_f32(f, f, 0, false);
    return (u8)(p & 0xFF);
}

// XCD-aware bijective swizzle of the (x,y) tile space. All per-z grids here
// have nwg % 8 == 0. Gives XCD k a contiguous tile-id chunk for L2 locality.
__device__ __forceinline__ void xcd_tile(int& tx, int& ty) {
    const int gx = gridDim.x;
    const int nwg = gx * gridDim.y;
    const int l = blockIdx.x + gx * blockIdx.y;
    const int per = nwg >> 3;
    const int swz = (l & 7) * per + (l >> 3);
    tx = swz % gx;
    ty = swz / gx;
}

#define GLOBAL_TO_LDS16(gp, lp)                                                           \
    __builtin_amdgcn_global_load_lds((const __attribute__((address_space(1))) void*)(gp), \
                                     (__attribute__((address_space(3))) void*)(lp), 16, 0, 0)

// ---------- bf16 GEMM: projections only (128^2, unchanged) ----------
__global__ __launch_bounds__(256, 2) void gemm_proj(
    const u16* __restrict__ A0, long sAz, int lda,
    const u16* __restrict__ Bp, long sBz, int ldb,
    u8* __restrict__ C8, long sCz, int ldc, int K,
    const float* __restrict__ bias, long sBiasZ) {
    __shared__ __align__(16) u16 As[128 * 64];
    __shared__ __align__(16) u16 Bs[128 * 64];

    const int tid  = threadIdx.x;
    const int lane = tid & 63;
    const int wave = tid >> 6;
    const int z    = blockIdx.z;

    const u16* a = A0 + (long)z * sAz;
    const u16* b = Bp + (long)z * sBz;

    int tx, ty;
    xcd_tile(tx, ty);
    const int tileM = ty * 128;
    const int tileN = tx * 128;

    const int wm  = wave >> 1;
    const int wn  = wave & 1;
    const int r16 = lane & 15;
    const int kg  = lane >> 4;

    const int srow = lane >> 3;
    const int sgc  = ((lane & 7) ^ (lane >> 3)) * 8;
    const int swb  = r16 & 7;

    f32x4 acc[4][4] = {};

    for (int k0 = 0; k0 < K; k0 += 64) {
#pragma unroll
        for (int p = 0; p < 4; p++) {
            const int rbase = p * 32 + wave * 8;
            GLOBAL_TO_LDS16(a + (long)(tileM + rbase + srow) * lda + k0 + sgc, &As[rbase * 64]);
            GLOBAL_TO_LDS16(b + (long)(tileN + rbase + srow) * ldb + k0 + sgc, &Bs[rbase * 64]);
        }
        __syncthreads();

        bf16x8 af[2][4], bfr[2][4];
#pragma unroll
        for (int h = 0; h < 2; h++) {
#pragma unroll
            for (int i = 0; i < 4; i++) {
                const int Ra = wm * 64 + i * 16 + r16;
                af[h][i]  = *(const bf16x8*)&As[Ra * 64 + (((h * 4 + kg) ^ swb)) * 8];
                const int Rb = wn * 64 + i * 16 + r16;
                bfr[h][i] = *(const bf16x8*)&Bs[Rb * 64 + (((h * 4 + kg) ^ swb)) * 8];
            }
        }
#pragma unroll
        for (int h = 0; h < 2; h++)
#pragma unroll
            for (int i = 0; i < 4; i++)
#pragma unroll
                for (int j = 0; j < 4; j++)
                    acc[i][j] = __builtin_amdgcn_mfma_f32_16x16x32_bf16(
                        af[h][i], bfr[h][j], acc[i][j], 0, 0, 0);
        __syncthreads();
    }

#pragma unroll
    for (int i = 0; i < 4; i++)
#pragma unroll
        for (int j = 0; j < 4; j++) {
            int col = tileN + wn * 64 + j * 16 + r16;
            float bv = bias[(long)z * sBiasZ + col];
#pragma unroll
            for (int v = 0; v < 4; v++) {
                int row = tileM + wm * 64 + i * 16 + kg * 4 + v;
                C8[(long)z * sCz + (long)row * ldc + col] = f2fp8(acc[i][j][v] + bv);
            }
        }
}

// ---------- fp8 GEMM, BM=256, 8 waves, pipelined (gate / sim / PV) ----------
// C = A[M,K](fp8) * B[N,K]^T(fp8). BK=128 bytes, dbuf LDS, XOR-swizzled.
// Pipeline: loads for step t+1 issued across step t's phases; one per-wave
// s_waitcnt vmcnt(0) at step start (drains exactly the needed loads; they had
// a full K-step of compute to land). Raw s_barrier only — no __syncthreads,
// so prefetch loads survive barriers.
// MODE 1: C16 = sigmoid(acc + bias[col])            (gate; A0->A1 @ kSplit)
// MODE 2: C8  = exp(acc*scale); atomicAdd row sums  (sim)
// MODE 4: C32 = cls + g16 * (acc / lsum[row])       (PV + merge)
template <int MODE, int BN, int WM, int WN>
__global__ __launch_bounds__(512, 2) void gemm8b(
    const u8* __restrict__ A0, const u8* __restrict__ A1, long sAz, int lda, int kSplit,
    const u8* __restrict__ Bp, long sBz, int ldb,
    void* __restrict__ Cp, long cOff, long sCz, int ldc, int K,
    const float* __restrict__ bias, const float* __restrict__ temp,
    const float* __restrict__ cls, const u16* __restrict__ g16,
    float* __restrict__ lsum, long lSz) {
    constexpr int BM  = 256;
    constexpr int BK  = 128;               // K bytes per step (fp8)
    constexpr int MR  = BM / WM / 16;      // frag rows per wave
    constexpr int NR  = BN / WN / 16;      // frag cols per wave
    constexpr int NPH = (MR / 2) * (NR / 2);  // phases per K-step (16 MFMA each)
    constexpr int BSTG = BN / 64;          // B stage ops per step (A is 4)

    __shared__ __align__(16) u8 As[2][BM * BK];
    __shared__ __align__(16) u8 Bs[2][BN * BK];

    const int tid  = threadIdx.x;
    const int lane = tid & 63;
    const int wave = tid >> 6;  // 0..7
    const int z    = blockIdx.z;

    const u8* a = A0 + (long)z * sAz;
    const u8* b = Bp + (long)z * sBz;

    int tx, ty;
    xcd_tile(tx, ty);
    const int tileM = ty * BM;
    const int tileN = tx * BN;

    const int wm  = wave / WN;
    const int wn  = wave % WN;
    const int r16 = lane & 15;
    const int kg  = lane >> 4;

    const int srow = lane >> 3;                        // row within 8-row slab
    const int sgc  = ((lane & 7) ^ (lane >> 3)) * 16;  // swizzled global byte col

    auto stageA = [&](int buf, int t, int p) {
        const u8* Ap = a;
        int kA = t * BK;
        if (MODE == 1 && kA >= kSplit) { Ap = A1; kA -= kSplit; }
        const int rbase = p * 64 + wave * 8;
        GLOBAL_TO_LDS16(Ap + (long)(tileM + rbase + srow) * lda + kA + sgc,
                        &As[buf][rbase * BK]);
    };
    auto stageB = [&](int buf, int t, int p) {
        const int rbase = p * 64 + wave * 8;
        GLOBAL_TO_LDS16(b + (long)(tileN + rbase + srow) * ldb + t * BK + sgc,
                        &Bs[buf][rbase * BK]);
    };

    f32x4 acc[MR][NR] = {};

    const int nt = K / BK;
    // prologue: stage step 0 into buf 0
#pragma unroll
    for (int p = 0; p < 4; p++) stageA(0, 0, p);
#pragma unroll
    for (int p = 0; p < BSTG; p++) stageB(0, 0, p);

    for (int t = 0; t < nt; t++) {
        const int cur = t & 1, nxt = cur ^ 1;
        const bool pf = (t + 1 < nt);
        // own stage loads for buf[cur] done -> barrier -> all waves' loads done
        asm volatile("s_waitcnt vmcnt(0)" ::: "memory");
        __builtin_amdgcn_s_barrier();
        asm volatile("" ::: "memory");

#pragma unroll
        for (int ph = 0; ph < NPH; ph++) {
            const int i0 = (ph / (NR / 2)) * 2;
            const int j0 = (ph % (NR / 2)) * 2;

            // ds-load this phase's operand subtile from buf[cur]
            long af[2][4], bfv[2][4];
#pragma unroll
            for (int ii = 0; ii < 2; ii++) {
                const int Ra = wm * (BM / WM) + (i0 + ii) * 16 + r16;
#pragma unroll
                for (int ks = 0; ks < 4; ks++) {
                    const int c = 2 * ks + (kg >> 1);
                    af[ii][ks] = *(const long*)&As[cur][Ra * BK + ((c ^ (Ra & 7)) << 4) + (kg & 1) * 8];
                }
            }
#pragma unroll
            for (int jj = 0; jj < 2; jj++) {
                const int Rb = wn * (BN / WN) + (j0 + jj) * 16 + r16;
#pragma unroll
                for (int ks = 0; ks < 4; ks++) {
                    const int c = 2 * ks + (kg >> 1);
                    bfv[jj][ks] = *(const long*)&Bs[cur][Rb * BK + ((c ^ (Rb & 7)) << 4) + (kg & 1) * 8];
                }
            }

            // issue prefetch chunk for step t+1 into buf[nxt]
            if (pf) {
                if (BN == 128) {
                    if (ph == 0) { stageA(nxt, t + 1, 0); stageA(nxt, t + 1, 1); }
                    if (ph == 1) { stageA(nxt, t + 1, 2); stageA(nxt, t + 1, 3); }
                    if (ph == 2) { stageB(nxt, t + 1, 0); }
                    if (ph == 3) { stageB(nxt, t + 1, 1); }
                } else {
                    if ((ph & 1) == 0) stageA(nxt, t + 1, ph >> 1);
                    else               stageB(nxt, t + 1, ph >> 1);
                }
            }

            __builtin_amdgcn_s_barrier();  // align waves pre-MFMA
            __builtin_amdgcn_s_setprio(1);
#pragma unroll
            for (int ks = 0; ks < 4; ks++)
#pragma unroll
                for (int ii = 0; ii < 2; ii++)
#pragma unroll
                    for (int jj = 0; jj < 2; jj++)
                        acc[i0 + ii][j0 + jj] = __builtin_amdgcn_mfma_f32_16x16x32_fp8_fp8(
                            af[ii][ks], bfv[jj][ks], acc[i0 + ii][j0 + jj], 0, 0, 0);
            __builtin_amdgcn_s_setprio(0);
            __builtin_amdgcn_s_barrier();  // phase end
            asm volatile("" ::: "memory");
        }
    }

    float scale = 1.0f;
    if (MODE == 2) scale = 1.0f / (32.0f * temp[0]);  // 1/(sqrt(1024)*temperature)

    u16*   C16 = (u16*)Cp;
    u8*    C8  = (u8*)Cp;
    float* C32 = (float*)Cp;

#pragma unroll
    for (int i = 0; i < MR; i++) {
        float rs[4] = {0.f, 0.f, 0.f, 0.f};
#pragma unroll
        for (int j = 0; j < NR; j++) {
            int col = tileN + wn * (BN / WN) + j * 16 + r16;
            float bv = (MODE == 1) ? bias[col] : 0.0f;
#pragma unroll
            for (int v = 0; v < 4; v++) {
                int row = tileM + wm * (BM / WM) + i * 16 + kg * 4 + v;
                long idx = cOff + (long)z * sCz + (long)row * ldc + col;
                float val = acc[i][j][v];
                if (MODE == 1) {
                    C16[idx] = f2bf(1.0f / (1.0f + __expf(-(val + bv))));
                } else if (MODE == 2) {
                    float e = __expf(val * scale);
                    C8[idx] = f2fp8(e);
                    rs[v] += e;
                } else {  // MODE 4
                    float inv = 1.0f / lsum[(long)z * lSz + row];
                    C32[idx] = cls[idx] + bf2f(g16[idx]) * (val * inv);
                }
            }
        }
        if (MODE == 2) {
#pragma unroll
            for (int v = 0; v < 4; v++) {
                float s = rs[v];
#pragma unroll
                for (int off = 1; off < 16; off <<= 1) s += __shfl_xor(s, off, 64);
                if (r16 == 0) {
                    int row = tileM + wm * (BM / WM) + i * 16 + kg * 4 + v;
                    atomicAdd(&lsum[(long)z * lSz + row], s);
                }
            }
        }
    }
}

// f32 -> bf16, vectorized x4
__global__ __launch_bounds__(256) void convert_bf16(const f32x4* __restrict__ s,
                                                    ushort4* __restrict__ d, long n4) {
    long i = (long)blockIdx.x * 256 + threadIdx.x;
    long stride = (long)gridDim.x * 256;
    for (; i < n4; i += stride) {
        f32x4 v = s[i];
        ushort4 o;
        o.x = f2bf(v.x); o.y = f2bf(v.y); o.z = f2bf(v.z); o.w = f2bf(v.w);
        d[i] = o;
    }
}

// f32 -> fp8 e4m3, vectorized x4
__global__ __launch_bounds__(256) void convert_fp8(const f32x4* __restrict__ s,
                                                   unsigned int* __restrict__ d, long n4) {
    long i = (long)blockIdx.x * 256 + threadIdx.x;
    long stride = (long)gridDim.x * 256;
    for (; i < n4; i += stride) {
        f32x4 v = s[i];
        int w = __builtin_amdgcn_cvt_pk_fp8_f32(v.x, v.y, 0, false);
        w = __builtin_amdgcn_cvt_pk_fp8_f32(v.z, v.w, w, true);
        d[i] = (unsigned int)w;
    }
}

__global__ __launch_bounds__(256) void zero_f32(float* __restrict__ p, int n) {
    int i = blockIdx.x * 256 + threadIdx.x;
    if (i < n) p[i] = 0.0f;
}

// qT8[b][d][t] = fp8(Q[b][t][d]), Q bf16
__global__ __launch_bounds__(256) void transpose_fp8(const u16* __restrict__ Q,
                                                     u8* __restrict__ QT, int S, int D) {
    __shared__ u8 tile[64][65];
    int bz = blockIdx.z;
    const u16* q = Q + (long)bz * S * D;
    u8* qt = QT + (long)bz * S * D;
    int t0 = blockIdx.x * 64;
    int d0 = blockIdx.y * 64;
    int c = threadIdx.x & 63;
    int r = threadIdx.x >> 6;
#pragma unroll
    for (int i = 0; i < 16; i++) {
        int tl = r + 4 * i;
        tile[tl][c] = f2fp8(bf2f(q[(long)(t0 + tl) * D + d0 + c]));
    }
    __syncthreads();
#pragma unroll
    for (int i = 0; i < 16; i++) {
        int dl = r + 4 * i;
        qt[(long)(d0 + dl) * S + t0 + c] = tile[c][dl];
    }
}

extern "C" void kernel_launch(void* const* d_in, const int* in_sizes, int n_in,
                              void* d_out, int out_size, void* d_ws, size_t ws_size,
                              hipStream_t stream) {
    (void)in_sizes; (void)n_in; (void)out_size;

    const float* classical = (const float*)d_in[0];
    const float* quantum   = (const float*)d_in[1];
    const float* Wc        = (const float*)d_in[2];
    const float* bc        = (const float*)d_in[3];
    const float* Wq        = (const float*)d_in[4];
    const float* bq        = (const float*)d_in[5];
    const float* Wg        = (const float*)d_in[6];
    const float* bg        = (const float*)d_in[7];
    const float* temp      = (const float*)d_in[8];
    float* out = (float*)d_out;

    const int B = 4, S = 2048, D = 1024;
    const long MD = (long)B * S * D;  // 8388608

    float* l       = (float*)d_ws;                 // B*S f32
    float* biasCat = l + (long)B * S;              // 2*D f32
    u16* cls_b = (u16*)(biasCat + 2 * D);          // MD u16 (g overlay after proj)
    u16* qnt_b = cls_b + MD;                       // MD u16
    u16* Wc_b  = qnt_b + MD;                       // D*D u16
    u16* Wq_b  = Wc_b + (long)D * D;               // D*D u16
    u8*  Wg8   = (u8*)(Wq_b + (long)D * D);        // D*2D bytes
    u8*  cp8   = Wg8 + (long)D * 2 * D;            // MD bytes
    u8*  qp8   = cp8 + MD;                         // MD bytes
    u8*  qT8   = qp8 + MD;                         // MD bytes
    u8*  P8    = qT8 + MD;                         // B*CH*S bytes
    u16* g     = cls_b;                            // overlay: cls_b dead after proj

    const size_t fixed_bytes = (size_t)B * S * 4 + 2 * D * 4 +
        (size_t)(2 * MD + 2 * (long)D * D) * 2 + (size_t)D * 2 * D + 3 * (size_t)MD;
    int CH = 256;
    for (int c = 2048; c >= 256; c >>= 1) {
        if (ws_size >= fixed_bytes + (size_t)B * c * S) { CH = c; break; }
    }

    dim3 blk(256);
    dim3 blk8(512);

    convert_bf16<<<1024, blk, 0, stream>>>((const f32x4*)classical, (ushort4*)cls_b, MD / 4);
    convert_bf16<<<1024, blk, 0, stream>>>((const f32x4*)quantum, (ushort4*)qnt_b, MD / 4);
    convert_bf16<<<256, blk, 0, stream>>>((const f32x4*)Wc, (ushort4*)Wc_b, (long)D * D / 4);
    convert_bf16<<<256, blk, 0, stream>>>((const f32x4*)Wq, (ushort4*)Wq_b, (long)D * D / 4);
    convert_fp8<<<512, blk, 0, stream>>>((const f32x4*)Wg, (unsigned int*)Wg8, (long)D * 2 * D / 4);
    hipMemcpyAsync(biasCat, bc, D * sizeof(float), hipMemcpyDeviceToDevice, stream);
    hipMemcpyAsync(biasCat + D, bq, D * sizeof(float), hipMemcpyDeviceToDevice, stream);
    zero_f32<<<dim3((B * S + 255) / 256), blk, 0, stream>>>(l, B * S);

    // fused projections (z=2): {cp8,qp8} = fp8({cls,qnt}@{Wc,Wq}^T + {bc,bq})
    gemm_proj<<<dim3(D / 128, (B * S) / 128, 2), blk, 0, stream>>>(
        cls_b, MD, D, Wc_b, (long)D * D, D, cp8, MD, D, D, biasCat, D);

    // gate: g = sigmoid([cp8|qp8]@Wg8^T + bg)  (bf16, overlays cls_b)
    // 256x128 tiles -> grid (8,32) = 256 blocks
    gemm8b<1, 128, 4, 2><<<dim3(D / 128, (B * S) / 256, 1), blk8, 0, stream>>>(
        cp8, qp8, 0, D, D, Wg8, 0, 2 * D, g, 0, 0, D, 2 * D,
        bg, nullptr, nullptr, nullptr, nullptr, 0);

    // quantum^T (fp8) per batch
    transpose_fp8<<<dim3(S / 64, D / 64, B), blk, 0, stream>>>(qnt_b, qT8, S, D);

    // attention, z-batched, CH-row chunks:
    //   P8 = fp8(exp(cp8@qp8^T/(32 t))), l += row sums; out = cls + g*(P8@qT8^T)/l
    for (int m0 = 0; m0 < S; m0 += CH) {
        // sim: 256x256 tiles -> grid (8, CH/256, 4)
        gemm8b<2, 256, 2, 4><<<dim3(S / 256, CH / 256, B), blk8, 0, stream>>>(
            cp8 + (long)m0 * D, nullptr, (long)S * D, D, 1 << 30,
            qp8, (long)S * D, D, P8, 0, (long)CH * S, S, D,
            nullptr, temp, nullptr, nullptr, l + m0, S);
        // PV+merge: 256x128 tiles -> grid (8, CH/256, 4)
        gemm8b<4, 128, 4, 2><<<dim3(D / 128, CH / 256, B), blk8, 0, stream>>>(
            P8, nullptr, (long)CH * S, S, 1 << 30, qT8, (long)D * S, S,
            out, (long)m0 * D, (long)S * D, D, S,
            nullptr, nullptr, classical, g, l + m0, S);
    }
}

// Round 3
// 291.331 us; speedup vs baseline: 1.2218x; 1.2218x over previous
//
#include <hip/hip_runtime.h>

// QuantumClassicalInterface on MI355X (gfx950). Round 11.
// f32 I/O. Projections: bf16 MFMA (128^2, BK=64, XOR swizzle), A reg-staged
// directly from f32 inputs (f2bf in-kernel) -> fp8 cp8/qp8.
// Gate/Sim/PV: fp8 e4m3 MFMA (128^2, BK=128, XOR swizzle, 32KB LDS) — the
// proven R9 2-barrier structure (R10's 8-phase port regressed; reverted).
// Softmax fused (exp + atomic row sums; logits bounded so no max-sub needed).
// PV epilogue does final merge: out = classical + g * (P@quantum)/l.
// R11: launch count 13 -> 6. convert_bf16(classical/quantum) eliminated
// (proj stages A from f32; transpose reads f32); biasCat memcpys eliminated
// (per-z bias pointers); Wc/Wq/Wg converts + l-zero fused into one prep kernel.

typedef unsigned short u16;
typedef unsigned char u8;
typedef __bf16 bf16x8 __attribute__((ext_vector_type(8)));
typedef float f32x4 __attribute__((ext_vector_type(4)));
typedef unsigned short ushort8 __attribute__((ext_vector_type(8)));

__device__ __forceinline__ u16 f2bf(float f) {
    unsigned int x;
    __builtin_memcpy(&x, &f, 4);
    unsigned int r = x + 0x7FFFu + ((x >> 16) & 1u);
    return (u16)(r >> 16);
}
__device__ __forceinline__ float bf2f(u16 u) {
    unsigned int x = ((unsigned int)u) << 16;
    float f;
    __builtin_memcpy(&f, &x, 4);
    return f;
}
__device__ __forceinline__ u8 f2fp8(float f) {
    int p = __builtin_amdgcn_cvt_pk_fp8_f32(f, f, 0, false);
    return (u8)(p & 0xFF);
}

// XCD-aware bijective swizzle of the (x,y) tile space. All per-z grids here
// have nwg % 8 == 0. Gives XCD k a contiguous tile-id chunk for L2 locality.
__device__ __forceinline__ void xcd_tile(int& tx, int& ty) {
    const int gx = gridDim.x;
    const int nwg = gx * gridDim.y;
    const int l = blockIdx.x + gx * blockIdx.y;
    const int per = nwg >> 3;
    const int swz = (l & 7) * per + (l >> 3);
    tx = swz % gx;
    ty = swz / gx;
}

#define GLOBAL_TO_LDS16(gp, lp)                                                           \
    __builtin_amdgcn_global_load_lds((const __attribute__((address_space(1))) void*)(gp), \
                                     (__attribute__((address_space(3))) void*)(lp), 16, 0, 0)

// ---------- bf16 GEMM: projections (A from f32, reg-staged) ----------
// C8(fp8) = A[M,K](f32->bf16) * B[N,K]^T(bf16) + bias[col]; z selects A/B/bias.
__global__ __launch_bounds__(256, 2) void gemm_proj(
    const float* __restrict__ Ac, const float* __restrict__ Aq, int lda,
    const u16* __restrict__ Bp, long sBz, int ldb,
    u8* __restrict__ C8, long sCz, int ldc, int K,
    const float* __restrict__ bc, const float* __restrict__ bq) {
    __shared__ __align__(16) u16 As[128 * 64];
    __shared__ __align__(16) u16 Bs[128 * 64];

    const int tid  = threadIdx.x;
    const int lane = tid & 63;
    const int wave = tid >> 6;
    const int z    = blockIdx.z;

    const float* a = z ? Aq : Ac;
    const u16* b = Bp + (long)z * sBz;
    const float* bias = z ? bq : bc;

    int tx, ty;
    xcd_tile(tx, ty);
    const int tileM = ty * 128;
    const int tileN = tx * 128;

    const int wm  = wave >> 1;
    const int wn  = wave & 1;
    const int r16 = lane & 15;
    const int kg  = lane >> 4;

    const int srow = lane >> 3;                       // 0..7
    const int sgc  = ((lane & 7) ^ srow) * 8;         // swizzled col (elems)
    const int swb  = r16 & 7;

    f32x4 acc[4][4] = {};

    for (int k0 = 0; k0 < K; k0 += 64) {
        // B: async global->LDS (bf16 weights), same layout/swizzle as before
#pragma unroll
        for (int p = 0; p < 4; p++) {
            const int rbase = p * 32 + wave * 8;
            GLOBAL_TO_LDS16(b + (long)(tileN + rbase + srow) * ldb + k0 + sgc, &Bs[rbase * 64]);
        }
        // A: reg-stage from f32 (8 floats/lane), convert, swizzled ds_write_b128.
        // LDS[row][chunk c] = global[row][c ^ (row&7)] — identical layout to the
        // old global_load_lds path, so the MFMA read side is unchanged.
#pragma unroll
        for (int p = 0; p < 4; p++) {
            const int rbase = p * 32 + wave * 8;
            const float* src = a + (long)(tileM + rbase + srow) * lda + k0 + sgc;
            f32x4 v0 = *(const f32x4*)src;
            f32x4 v1 = *(const f32x4*)(src + 4);
            ushort8 w;
            w[0] = f2bf(v0.x); w[1] = f2bf(v0.y); w[2] = f2bf(v0.z); w[3] = f2bf(v0.w);
            w[4] = f2bf(v1.x); w[5] = f2bf(v1.y); w[6] = f2bf(v1.z); w[7] = f2bf(v1.w);
            *(ushort8*)&As[rbase * 64 + lane * 8] = w;
        }
        __syncthreads();

        bf16x8 af[2][4], bfr[2][4];
#pragma unroll
        for (int h = 0; h < 2; h++) {
#pragma unroll
            for (int i = 0; i < 4; i++) {
                const int Ra = wm * 64 + i * 16 + r16;
                af[h][i]  = *(const bf16x8*)&As[Ra * 64 + (((h * 4 + kg) ^ swb)) * 8];
                const int Rb = wn * 64 + i * 16 + r16;
                bfr[h][i] = *(const bf16x8*)&Bs[Rb * 64 + (((h * 4 + kg) ^ swb)) * 8];
            }
        }
#pragma unroll
        for (int h = 0; h < 2; h++)
#pragma unroll
            for (int i = 0; i < 4; i++)
#pragma unroll
                for (int j = 0; j < 4; j++)
                    acc[i][j] = __builtin_amdgcn_mfma_f32_16x16x32_bf16(
                        af[h][i], bfr[h][j], acc[i][j], 0, 0, 0);
        __syncthreads();
    }

#pragma unroll
    for (int i = 0; i < 4; i++)
#pragma unroll
        for (int j = 0; j < 4; j++) {
            int col = tileN + wn * 64 + j * 16 + r16;
            float bv = bias[col];
#pragma unroll
            for (int v = 0; v < 4; v++) {
                int row = tileM + wm * 64 + i * 16 + kg * 4 + v;
                C8[(long)z * sCz + (long)row * ldc + col] = f2fp8(acc[i][j][v] + bv);
            }
        }
}

// ---------- fp8 GEMM: gate / sim / PV (proven R9 structure) ----------
// C = A[M,K](fp8) * B[N,K]^T(fp8). BK=128, 32KB LDS, XOR-swizzled 16B chunks.
// MODE 1: C16 = sigmoid(acc + bias[col])            (gate -> g bf16; A0->A1 @ kSplit)
// MODE 2: C8  = exp(acc*scale); atomicAdd row sums  (sim)
// MODE 4: C32 = cls + g16 * (acc / lsum[row])       (PV + merge)
template <int MODE>
__global__ __launch_bounds__(256, 2) void gemm8(
    const u8* __restrict__ A0, const u8* __restrict__ A1, long sAz, int lda, int kSplit,
    const u8* __restrict__ Bp, long sBz, int ldb,
    void* __restrict__ Cp, long cOff, long sCz, int ldc, int K,
    const float* __restrict__ bias, const float* __restrict__ temp,
    const float* __restrict__ cls, const u16* __restrict__ g16,
    float* __restrict__ lsum, long lSz) {
    __shared__ __align__(16) u8 As[128 * 128];
    __shared__ __align__(16) u8 Bs[128 * 128];

    const int tid  = threadIdx.x;
    const int lane = tid & 63;
    const int wave = tid >> 6;
    const int z    = blockIdx.z;

    const u8* a = A0 + (long)z * sAz;
    const u8* b = Bp + (long)z * sBz;

    int tx, ty;
    xcd_tile(tx, ty);
    const int tileM = ty * 128;
    const int tileN = tx * 128;

    const int wm  = wave >> 1;
    const int wn  = wave & 1;
    const int r16 = lane & 15;
    const int kg  = lane >> 4;

    const int srow = lane >> 3;                        // 0..7 (row within 8-row slab)
    const int sgc  = ((lane & 7) ^ (lane >> 3)) * 16;  // swizzled global byte col

    f32x4 acc[4][4] = {};

    for (int k0 = 0; k0 < K; k0 += 128) {
        const u8* Ap = a;
        int kA = k0;
        if (MODE == 1 && k0 >= kSplit) { Ap = A1; kA = k0 - kSplit; }

#pragma unroll
        for (int p = 0; p < 4; p++) {
            const int rbase = p * 32 + wave * 8;
            GLOBAL_TO_LDS16(Ap + (long)(tileM + rbase + srow) * lda + kA + sgc, &As[rbase * 128]);
            GLOBAL_TO_LDS16(b + (long)(tileN + rbase + srow) * ldb + k0 + sgc, &Bs[rbase * 128]);
        }
        __syncthreads();

#pragma unroll
        for (int h = 0; h < 4; h++) {
            long af[4], bfr[4];
#pragma unroll
            for (int i = 0; i < 4; i++) {
                const int Ra = wm * 64 + i * 16 + r16;
                af[i]  = *(const long*)&As[Ra * 128 + (((h * 2 + (kg >> 1)) ^ (Ra & 7))) * 16 + (kg & 1) * 8];
                const int Rb = wn * 64 + i * 16 + r16;
                bfr[i] = *(const long*)&Bs[Rb * 128 + (((h * 2 + (kg >> 1)) ^ (Rb & 7))) * 16 + (kg & 1) * 8];
            }
#pragma unroll
            for (int i = 0; i < 4; i++)
#pragma unroll
                for (int j = 0; j < 4; j++)
                    acc[i][j] = __builtin_amdgcn_mfma_f32_16x16x32_fp8_fp8(
                        af[i], bfr[j], acc[i][j], 0, 0, 0);
        }
        __syncthreads();
    }

    float scale = 1.0f;
    if (MODE == 2) scale = 1.0f / (32.0f * temp[0]);  // 1/(sqrt(1024)*temperature)

    u16*   C16 = (u16*)Cp;
    u8*    C8  = (u8*)Cp;
    float* C32 = (float*)Cp;

#pragma unroll
    for (int i = 0; i < 4; i++) {
        float rs[4] = {0.f, 0.f, 0.f, 0.f};
#pragma unroll
        for (int j = 0; j < 4; j++) {
            int col = tileN + wn * 64 + j * 16 + r16;
            float bv = (MODE == 1) ? bias[col] : 0.0f;
#pragma unroll
            for (int v = 0; v < 4; v++) {
                int row = tileM + wm * 64 + i * 16 + kg * 4 + v;
                long idx = cOff + (long)z * sCz + (long)row * ldc + col;
                float val = acc[i][j][v];
                if (MODE == 1) {
                    C16[idx] = f2bf(1.0f / (1.0f + __expf(-(val + bv))));
                } else if (MODE == 2) {
                    float e = __expf(val * scale);
                    C8[idx] = f2fp8(e);
                    rs[v] += e;
                } else {  // MODE 4
                    float inv = 1.0f / lsum[(long)z * lSz + row];
                    C32[idx] = cls[idx] + bf2f(g16[idx]) * (val * inv);
                }
            }
        }
        if (MODE == 2) {
#pragma unroll
            for (int v = 0; v < 4; v++) {
                float s = rs[v];
#pragma unroll
                for (int off = 1; off < 16; off <<= 1) s += __shfl_xor(s, off, 64);
                if (r16 == 0) {
                    int row = tileM + wm * 64 + i * 16 + kg * 4 + v;
                    atomicAdd(&lsum[(long)z * lSz + row], s);
                }
            }
        }
    }
}

// Fused prep: Wc->bf16, Wq->bf16, Wg->fp8, l->0. One launch.
__global__ __launch_bounds__(256) void prep(
    const f32x4* __restrict__ Wc, const f32x4* __restrict__ Wq, const f32x4* __restrict__ Wg,
    ushort4* __restrict__ WcB, ushort4* __restrict__ WqB, unsigned int* __restrict__ Wg8,
    f32x4* __restrict__ l, long nW, long nG, long nL) {
    long i = (long)blockIdx.x * 256 + threadIdx.x;
    long stride = (long)gridDim.x * 256;
    long total = 2 * nW + nG + nL;
    for (; i < total; i += stride) {
        if (i < 2 * nW) {
            long j = (i < nW) ? i : i - nW;
            f32x4 v = (i < nW) ? Wc[j] : Wq[j];
            ushort4 o;
            o.x = f2bf(v.x); o.y = f2bf(v.y); o.z = f2bf(v.z); o.w = f2bf(v.w);
            if (i < nW) WcB[j] = o; else WqB[j] = o;
        } else if (i < 2 * nW + nG) {
            long j = i - 2 * nW;
            f32x4 v = Wg[j];
            int w = __builtin_amdgcn_cvt_pk_fp8_f32(v.x, v.y, 0, false);
            w = __builtin_amdgcn_cvt_pk_fp8_f32(v.z, v.w, w, true);
            Wg8[j] = (unsigned int)w;
        } else {
            l[i - 2 * nW - nG] = (f32x4){0.f, 0.f, 0.f, 0.f};
        }
    }
}

// qT8[b][d][t] = fp8(Q[b][t][d]), Q f32
__global__ __launch_bounds__(256) void transpose_fp8(const float* __restrict__ Q,
                                                     u8* __restrict__ QT, int S, int D) {
    __shared__ u8 tile[64][65];
    int bz = blockIdx.z;
    const float* q = Q + (long)bz * S * D;
    u8* qt = QT + (long)bz * S * D;
    int t0 = blockIdx.x * 64;
    int d0 = blockIdx.y * 64;
    int c = threadIdx.x & 63;
    int r = threadIdx.x >> 6;
#pragma unroll
    for (int i = 0; i < 16; i++) {
        int tl = r + 4 * i;
        tile[tl][c] = f2fp8(q[(long)(t0 + tl) * D + d0 + c]);
    }
    __syncthreads();
#pragma unroll
    for (int i = 0; i < 16; i++) {
        int dl = r + 4 * i;
        qt[(long)(d0 + dl) * S + t0 + c] = tile[c][dl];
    }
}

extern "C" void kernel_launch(void* const* d_in, const int* in_sizes, int n_in,
                              void* d_out, int out_size, void* d_ws, size_t ws_size,
                              hipStream_t stream) {
    (void)in_sizes; (void)n_in; (void)out_size;

    const float* classical = (const float*)d_in[0];
    const float* quantum   = (const float*)d_in[1];
    const float* Wc        = (const float*)d_in[2];
    const float* bc        = (const float*)d_in[3];
    const float* Wq        = (const float*)d_in[4];
    const float* bq        = (const float*)d_in[5];
    const float* Wg        = (const float*)d_in[6];
    const float* bg        = (const float*)d_in[7];
    const float* temp      = (const float*)d_in[8];
    float* out = (float*)d_out;

    const int B = 4, S = 2048, D = 1024;
    const long MD = (long)B * S * D;  // 8388608

    float* l    = (float*)d_ws;                    // B*S f32
    u16* Wc_b   = (u16*)(l + (long)B * S);         // D*D u16
    u16* Wq_b   = Wc_b + (long)D * D;              // D*D u16
    u8*  Wg8    = (u8*)(Wq_b + (long)D * D);       // D*2D bytes
    u16* g      = (u16*)(Wg8 + (long)D * 2 * D);   // MD u16
    u8*  cp8    = (u8*)(g + MD);                   // MD bytes
    u8*  qp8    = cp8 + MD;                        // MD bytes
    u8*  qT8    = qp8 + MD;                        // MD bytes
    u8*  P8     = qT8 + MD;                        // B*CH*S bytes

    const size_t fixed_bytes = (size_t)B * S * 4 + 2 * (size_t)D * D * 2 +
        (size_t)D * 2 * D + (size_t)MD * 2 + 3 * (size_t)MD;
    int CH = 128;
    for (int c = 2048; c >= 128; c >>= 1) {
        if (ws_size >= fixed_bytes + (size_t)B * c * S) { CH = c; break; }
    }

    dim3 blk(256);

    // prep: Wc/Wq -> bf16, Wg -> fp8, l -> 0 (one launch)
    prep<<<1024, blk, 0, stream>>>(
        (const f32x4*)Wc, (const f32x4*)Wq, (const f32x4*)Wg,
        (ushort4*)Wc_b, (ushort4*)Wq_b, (unsigned int*)Wg8,
        (f32x4*)l, (long)D * D / 4, (long)D * 2 * D / 4, (long)B * S / 4);

    // fused projections (z=2): {cp8,qp8} = fp8({cls,qnt}@{Wc,Wq}^T + {bc,bq})
    // A reg-staged directly from f32 inputs.
    gemm_proj<<<dim3(D / 128, (B * S) / 128, 2), blk, 0, stream>>>(
        classical, quantum, D, Wc_b, (long)D * D, D, cp8, MD, D, D, bc, bq);

    // gate: g = sigmoid([cp8|qp8]@Wg8^T + bg)  (bf16)
    gemm8<1><<<dim3(D / 128, (B * S) / 128, 1), blk, 0, stream>>>(
        cp8, qp8, 0, D, D, Wg8, 0, 2 * D, g, 0, 0, D, 2 * D,
        bg, nullptr, nullptr, nullptr, nullptr, 0);

    // quantum^T (fp8) per batch, from f32 directly
    transpose_fp8<<<dim3(S / 64, D / 64, B), blk, 0, stream>>>(quantum, qT8, S, D);

    // attention, z-batched, CH-row chunks:
    //   P8 = fp8(exp(cp8@qp8^T/(32 t))), l += row sums; out = cls + g*(P8@qT8^T)/l
    for (int m0 = 0; m0 < S; m0 += CH) {
        gemm8<2><<<dim3(S / 128, CH / 128, B), blk, 0, stream>>>(
            cp8 + (long)m0 * D, nullptr, (long)S * D, D, 1 << 30,
            qp8, (long)S * D, D, P8, 0, (long)CH * S, S, D,
            nullptr, temp, nullptr, nullptr, l + m0, S);
        gemm8<4><<<dim3(D / 128, CH / 128, B), blk, 0, stream>>>(
            P8, nullptr, (long)CH * S, S, 1 << 30, qT8, (long)D * S, S,
            out, (long)m0 * D, (long)S * D, D, S,
            nullptr, nullptr, classical, g, l + m0, S);
    }
}

// Round 4
// 266.195 us; speedup vs baseline: 1.3371x; 1.0944x over previous
//
#include <hip/hip_runtime.h>

// QuantumClassicalInterface on MI355X (gfx950). Round 12.
// f32 I/O. One fused prep kernel: cls/qnt -> bf16, Wc/Wq -> bf16, Wg -> fp8,
// l -> 0. Projections: bf16 MFMA (128^2, BK=64, XOR swizzle, global_load_lds
// both operands — R9-proven body) -> fp8 cp8/qp8.
// Gate/Sim/PV: fp8 e4m3 MFMA (128^2, BK=128, XOR swizzle, 32KB LDS, 2-barrier).
// Softmax fused (exp + atomic row sums; logits bounded so no max-sub needed).
// PV epilogue does final merge: out = classical + g * (P@quantum)/l.
// R12: reverted R11's f32-direct A staging in proj (latency-serialized, 81us);
// kept launch consolidation (6 launches), per-z bias pointers, g overlay.

typedef unsigned short u16;
typedef unsigned char u8;
typedef __bf16 bf16x8 __attribute__((ext_vector_type(8)));
typedef float f32x4 __attribute__((ext_vector_type(4)));

__device__ __forceinline__ u16 f2bf(float f) {
    unsigned int x;
    __builtin_memcpy(&x, &f, 4);
    unsigned int r = x + 0x7FFFu + ((x >> 16) & 1u);
    return (u16)(r >> 16);
}
__device__ __forceinline__ float bf2f(u16 u) {
    unsigned int x = ((unsigned int)u) << 16;
    float f;
    __builtin_memcpy(&f, &x, 4);
    return f;
}
__device__ __forceinline__ u8 f2fp8(float f) {
    int p = __builtin_amdgcn_cvt_pk_fp8_f32(f, f, 0, false);
    return (u8)(p & 0xFF);
}

// XCD-aware bijective swizzle of the (x,y) tile space. All per-z grids here
// have nwg % 8 == 0. Gives XCD k a contiguous tile-id chunk for L2 locality.
__device__ __forceinline__ void xcd_tile(int& tx, int& ty) {
    const int gx = gridDim.x;
    const int nwg = gx * gridDim.y;
    const int l = blockIdx.x + gx * blockIdx.y;
    const int per = nwg >> 3;
    const int swz = (l & 7) * per + (l >> 3);
    tx = swz % gx;
    ty = swz / gx;
}

#define GLOBAL_TO_LDS16(gp, lp)                                                           \
    __builtin_amdgcn_global_load_lds((const __attribute__((address_space(1))) void*)(gp), \
                                     (__attribute__((address_space(3))) void*)(lp), 16, 0, 0)

// ---------- bf16 GEMM: projections (R9-proven body, per-z pointers) ----------
// C8(fp8) = A[M,K](bf16) * B[N,K]^T(bf16) + bias[col]; z selects A/B/bias.
__global__ __launch_bounds__(256, 2) void gemm_proj(
    const u16* __restrict__ Ac, const u16* __restrict__ Aq, int lda,
    const u16* __restrict__ Bp, long sBz, int ldb,
    u8* __restrict__ C8, long sCz, int ldc, int K,
    const float* __restrict__ bc, const float* __restrict__ bq) {
    __shared__ __align__(16) u16 As[128 * 64];
    __shared__ __align__(16) u16 Bs[128 * 64];

    const int tid  = threadIdx.x;
    const int lane = tid & 63;
    const int wave = tid >> 6;
    const int z    = blockIdx.z;

    const u16* a = z ? Aq : Ac;
    const u16* b = Bp + (long)z * sBz;
    const float* bias = z ? bq : bc;

    int tx, ty;
    xcd_tile(tx, ty);
    const int tileM = ty * 128;
    const int tileN = tx * 128;

    const int wm  = wave >> 1;
    const int wn  = wave & 1;
    const int r16 = lane & 15;
    const int kg  = lane >> 4;

    const int srow = lane >> 3;                       // 0..7
    const int sgc  = ((lane & 7) ^ (lane >> 3)) * 8;  // swizzled global col (elems)
    const int swb  = r16 & 7;

    f32x4 acc[4][4] = {};

    for (int k0 = 0; k0 < K; k0 += 64) {
#pragma unroll
        for (int p = 0; p < 4; p++) {
            const int rbase = p * 32 + wave * 8;
            GLOBAL_TO_LDS16(a + (long)(tileM + rbase + srow) * lda + k0 + sgc, &As[rbase * 64]);
            GLOBAL_TO_LDS16(b + (long)(tileN + rbase + srow) * ldb + k0 + sgc, &Bs[rbase * 64]);
        }
        __syncthreads();

        bf16x8 af[2][4], bfr[2][4];
#pragma unroll
        for (int h = 0; h < 2; h++) {
#pragma unroll
            for (int i = 0; i < 4; i++) {
                const int Ra = wm * 64 + i * 16 + r16;
                af[h][i]  = *(const bf16x8*)&As[Ra * 64 + (((h * 4 + kg) ^ swb)) * 8];
                const int Rb = wn * 64 + i * 16 + r16;
                bfr[h][i] = *(const bf16x8*)&Bs[Rb * 64 + (((h * 4 + kg) ^ swb)) * 8];
            }
        }
#pragma unroll
        for (int h = 0; h < 2; h++)
#pragma unroll
            for (int i = 0; i < 4; i++)
#pragma unroll
                for (int j = 0; j < 4; j++)
                    acc[i][j] = __builtin_amdgcn_mfma_f32_16x16x32_bf16(
                        af[h][i], bfr[h][j], acc[i][j], 0, 0, 0);
        __syncthreads();
    }

#pragma unroll
    for (int i = 0; i < 4; i++)
#pragma unroll
        for (int j = 0; j < 4; j++) {
            int col = tileN + wn * 64 + j * 16 + r16;
            float bv = bias[col];
#pragma unroll
            for (int v = 0; v < 4; v++) {
                int row = tileM + wm * 64 + i * 16 + kg * 4 + v;
                C8[(long)z * sCz + (long)row * ldc + col] = f2fp8(acc[i][j][v] + bv);
            }
        }
}

// ---------- fp8 GEMM: gate / sim / PV (proven R9 structure) ----------
// C = A[M,K](fp8) * B[N,K]^T(fp8). BK=128, 32KB LDS, XOR-swizzled 16B chunks.
// MODE 1: C16 = sigmoid(acc + bias[col])            (gate -> g bf16; A0->A1 @ kSplit)
// MODE 2: C8  = exp(acc*scale); atomicAdd row sums  (sim)
// MODE 4: C32 = cls + g16 * (acc / lsum[row])       (PV + merge)
template <int MODE>
__global__ __launch_bounds__(256, 2) void gemm8(
    const u8* __restrict__ A0, const u8* __restrict__ A1, long sAz, int lda, int kSplit,
    const u8* __restrict__ Bp, long sBz, int ldb,
    void* __restrict__ Cp, long cOff, long sCz, int ldc, int K,
    const float* __restrict__ bias, const float* __restrict__ temp,
    const float* __restrict__ cls, const u16* __restrict__ g16,
    float* __restrict__ lsum, long lSz) {
    __shared__ __align__(16) u8 As[128 * 128];
    __shared__ __align__(16) u8 Bs[128 * 128];

    const int tid  = threadIdx.x;
    const int lane = tid & 63;
    const int wave = tid >> 6;
    const int z    = blockIdx.z;

    const u8* a = A0 + (long)z * sAz;
    const u8* b = Bp + (long)z * sBz;

    int tx, ty;
    xcd_tile(tx, ty);
    const int tileM = ty * 128;
    const int tileN = tx * 128;

    const int wm  = wave >> 1;
    const int wn  = wave & 1;
    const int r16 = lane & 15;
    const int kg  = lane >> 4;

    const int srow = lane >> 3;                        // 0..7 (row within 8-row slab)
    const int sgc  = ((lane & 7) ^ (lane >> 3)) * 16;  // swizzled global byte col

    f32x4 acc[4][4] = {};

    for (int k0 = 0; k0 < K; k0 += 128) {
        const u8* Ap = a;
        int kA = k0;
        if (MODE == 1 && k0 >= kSplit) { Ap = A1; kA = k0 - kSplit; }

#pragma unroll
        for (int p = 0; p < 4; p++) {
            const int rbase = p * 32 + wave * 8;
            GLOBAL_TO_LDS16(Ap + (long)(tileM + rbase + srow) * lda + kA + sgc, &As[rbase * 128]);
            GLOBAL_TO_LDS16(b + (long)(tileN + rbase + srow) * ldb + k0 + sgc, &Bs[rbase * 128]);
        }
        __syncthreads();

#pragma unroll
        for (int h = 0; h < 4; h++) {
            long af[4], bfr[4];
#pragma unroll
            for (int i = 0; i < 4; i++) {
                const int Ra = wm * 64 + i * 16 + r16;
                af[i]  = *(const long*)&As[Ra * 128 + (((h * 2 + (kg >> 1)) ^ (Ra & 7))) * 16 + (kg & 1) * 8];
                const int Rb = wn * 64 + i * 16 + r16;
                bfr[i] = *(const long*)&Bs[Rb * 128 + (((h * 2 + (kg >> 1)) ^ (Rb & 7))) * 16 + (kg & 1) * 8];
            }
#pragma unroll
            for (int i = 0; i < 4; i++)
#pragma unroll
                for (int j = 0; j < 4; j++)
                    acc[i][j] = __builtin_amdgcn_mfma_f32_16x16x32_fp8_fp8(
                        af[i], bfr[j], acc[i][j], 0, 0, 0);
        }
        __syncthreads();
    }

    float scale = 1.0f;
    if (MODE == 2) scale = 1.0f / (32.0f * temp[0]);  // 1/(sqrt(1024)*temperature)

    u16*   C16 = (u16*)Cp;
    u8*    C8  = (u8*)Cp;
    float* C32 = (float*)Cp;

#pragma unroll
    for (int i = 0; i < 4; i++) {
        float rs[4] = {0.f, 0.f, 0.f, 0.f};
#pragma unroll
        for (int j = 0; j < 4; j++) {
            int col = tileN + wn * 64 + j * 16 + r16;
            float bv = (MODE == 1) ? bias[col] : 0.0f;
#pragma unroll
            for (int v = 0; v < 4; v++) {
                int row = tileM + wm * 64 + i * 16 + kg * 4 + v;
                long idx = cOff + (long)z * sCz + (long)row * ldc + col;
                float val = acc[i][j][v];
                if (MODE == 1) {
                    C16[idx] = f2bf(1.0f / (1.0f + __expf(-(val + bv))));
                } else if (MODE == 2) {
                    float e = __expf(val * scale);
                    C8[idx] = f2fp8(e);
                    rs[v] += e;
                } else {  // MODE 4
                    float inv = 1.0f / lsum[(long)z * lSz + row];
                    C32[idx] = cls[idx] + bf2f(g16[idx]) * (val * inv);
                }
            }
        }
        if (MODE == 2) {
#pragma unroll
            for (int v = 0; v < 4; v++) {
                float s = rs[v];
#pragma unroll
                for (int off = 1; off < 16; off <<= 1) s += __shfl_xor(s, off, 64);
                if (r16 == 0) {
                    int row = tileM + wm * 64 + i * 16 + kg * 4 + v;
                    atomicAdd(&lsum[(long)z * lSz + row], s);
                }
            }
        }
    }
}

// Fused prep: cls->bf16, qnt->bf16, Wc->bf16, Wq->bf16, Wg->fp8, l->0.
__global__ __launch_bounds__(256) void prep(
    const f32x4* __restrict__ cls, const f32x4* __restrict__ qnt,
    const f32x4* __restrict__ Wc, const f32x4* __restrict__ Wq, const f32x4* __restrict__ Wg,
    ushort4* __restrict__ clsB, ushort4* __restrict__ qntB,
    ushort4* __restrict__ WcB, ushort4* __restrict__ WqB, unsigned int* __restrict__ Wg8,
    f32x4* __restrict__ l, long nM, long nW, long nG, long nL) {
    long i = (long)blockIdx.x * 256 + threadIdx.x;
    long stride = (long)gridDim.x * 256;
    long total = 2 * nM + 2 * nW + nG + nL;
    for (; i < total; i += stride) {
        if (i < 2 * nM) {
            long j = (i < nM) ? i : i - nM;
            f32x4 v = (i < nM) ? cls[j] : qnt[j];
            ushort4 o;
            o.x = f2bf(v.x); o.y = f2bf(v.y); o.z = f2bf(v.z); o.w = f2bf(v.w);
            if (i < nM) clsB[j] = o; else qntB[j] = o;
        } else if (i < 2 * nM + 2 * nW) {
            long j = i - 2 * nM;
            long k = (j < nW) ? j : j - nW;
            f32x4 v = (j < nW) ? Wc[k] : Wq[k];
            ushort4 o;
            o.x = f2bf(v.x); o.y = f2bf(v.y); o.z = f2bf(v.z); o.w = f2bf(v.w);
            if (j < nW) WcB[k] = o; else WqB[k] = o;
        } else if (i < 2 * nM + 2 * nW + nG) {
            long j = i - 2 * nM - 2 * nW;
            f32x4 v = Wg[j];
            int w = __builtin_amdgcn_cvt_pk_fp8_f32(v.x, v.y, 0, false);
            w = __builtin_amdgcn_cvt_pk_fp8_f32(v.z, v.w, w, true);
            Wg8[j] = (unsigned int)w;
        } else {
            l[i - 2 * nM - 2 * nW - nG] = (f32x4){0.f, 0.f, 0.f, 0.f};
        }
    }
}

// qT8[b][d][t] = fp8(Q[b][t][d]), Q bf16
__global__ __launch_bounds__(256) void transpose_fp8(const u16* __restrict__ Q,
                                                     u8* __restrict__ QT, int S, int D) {
    __shared__ u8 tile[64][65];
    int bz = blockIdx.z;
    const u16* q = Q + (long)bz * S * D;
    u8* qt = QT + (long)bz * S * D;
    int t0 = blockIdx.x * 64;
    int d0 = blockIdx.y * 64;
    int c = threadIdx.x & 63;
    int r = threadIdx.x >> 6;
#pragma unroll
    for (int i = 0; i < 16; i++) {
        int tl = r + 4 * i;
        tile[tl][c] = f2fp8(bf2f(q[(long)(t0 + tl) * D + d0 + c]));
    }
    __syncthreads();
#pragma unroll
    for (int i = 0; i < 16; i++) {
        int dl = r + 4 * i;
        qt[(long)(d0 + dl) * S + t0 + c] = tile[c][dl];
    }
}

extern "C" void kernel_launch(void* const* d_in, const int* in_sizes, int n_in,
                              void* d_out, int out_size, void* d_ws, size_t ws_size,
                              hipStream_t stream) {
    (void)in_sizes; (void)n_in; (void)out_size;

    const float* classical = (const float*)d_in[0];
    const float* quantum   = (const float*)d_in[1];
    const float* Wc        = (const float*)d_in[2];
    const float* bc        = (const float*)d_in[3];
    const float* Wq        = (const float*)d_in[4];
    const float* bq        = (const float*)d_in[5];
    const float* Wg        = (const float*)d_in[6];
    const float* bg        = (const float*)d_in[7];
    const float* temp      = (const float*)d_in[8];
    float* out = (float*)d_out;

    const int B = 4, S = 2048, D = 1024;
    const long MD = (long)B * S * D;  // 8388608

    float* l    = (float*)d_ws;                    // B*S f32
    u16* Wc_b   = (u16*)(l + (long)B * S);         // D*D u16
    u16* Wq_b   = Wc_b + (long)D * D;              // D*D u16
    u8*  Wg8    = (u8*)(Wq_b + (long)D * D);       // D*2D bytes
    u16* cls_b  = (u16*)(Wg8 + (long)D * 2 * D);   // MD u16 (g overlay after proj)
    u16* qnt_b  = cls_b + MD;                      // MD u16
    u8*  cp8    = (u8*)(qnt_b + MD);               // MD bytes
    u8*  qp8    = cp8 + MD;                        // MD bytes
    u8*  qT8    = qp8 + MD;                        // MD bytes
    u8*  P8     = qT8 + MD;                        // B*CH*S bytes
    u16* g      = cls_b;                           // overlay: cls_b dead after proj

    const size_t fixed_bytes = (size_t)B * S * 4 + 2 * (size_t)D * D * 2 +
        (size_t)D * 2 * D + 2 * (size_t)MD * 2 + 3 * (size_t)MD;
    int CH = 128;
    for (int c = 2048; c >= 128; c >>= 1) {
        if (ws_size >= fixed_bytes + (size_t)B * c * S) { CH = c; break; }
    }

    dim3 blk(256);

    // prep: cls/qnt -> bf16, Wc/Wq -> bf16, Wg -> fp8, l -> 0 (one launch)
    prep<<<2048, blk, 0, stream>>>(
        (const f32x4*)classical, (const f32x4*)quantum,
        (const f32x4*)Wc, (const f32x4*)Wq, (const f32x4*)Wg,
        (ushort4*)cls_b, (ushort4*)qnt_b,
        (ushort4*)Wc_b, (ushort4*)Wq_b, (unsigned int*)Wg8,
        (f32x4*)l, MD / 4, (long)D * D / 4, (long)D * 2 * D / 4, (long)B * S / 4);

    // fused projections (z=2): {cp8,qp8} = fp8({cls,qnt}@{Wc,Wq}^T + {bc,bq})
    gemm_proj<<<dim3(D / 128, (B * S) / 128, 2), blk, 0, stream>>>(
        cls_b, qnt_b, D, Wc_b, (long)D * D, D, cp8, MD, D, D, bc, bq);

    // gate: g = sigmoid([cp8|qp8]@Wg8^T + bg)  (bf16, overlays cls_b)
    gemm8<1><<<dim3(D / 128, (B * S) / 128, 1), blk, 0, stream>>>(
        cp8, qp8, 0, D, D, Wg8, 0, 2 * D, g, 0, 0, D, 2 * D,
        bg, nullptr, nullptr, nullptr, nullptr, 0);

    // quantum^T (fp8) per batch
    transpose_fp8<<<dim3(S / 64, D / 64, B), blk, 0, stream>>>(qnt_b, qT8, S, D);

    // attention, z-batched, CH-row chunks:
    //   P8 = fp8(exp(cp8@qp8^T/(32 t))), l += row sums; out = cls + g*(P8@qT8^T)/l
    for (int m0 = 0; m0 < S; m0 += CH) {
        gemm8<2><<<dim3(S / 128, CH / 128, B), blk, 0, stream>>>(
            cp8 + (long)m0 * D, nullptr, (long)S * D, D, 1 << 30,
            qp8, (long)S * D, D, P8, 0, (long)CH * S, S, D,
            nullptr, temp, nullptr, nullptr, l + m0, S);
        gemm8<4><<<dim3(D / 128, CH / 128, B), blk, 0, stream>>>(
            P8, nullptr, (long)CH * S, S, 1 << 30, qT8, (long)D * S, S,
            out, (long)m0 * D, (long)S * D, D, S,
            nullptr, nullptr, classical, g, l + m0, S);
    }
}